// Round 5
// baseline (304.379 us; speedup 1.0000x reference)
//
#include <hip/hip_runtime.h>

#define CIN 64
#define COUT 32

typedef __attribute__((ext_vector_type(8))) short bf16x8;
typedef __attribute__((ext_vector_type(4))) float f32x4;

__device__ inline ushort f2bf(float x) {
    union { float f; unsigned u; } v; v.f = x;
    unsigned r = v.u + 0x7fff + ((v.u >> 16) & 1);   // RNE
    return (ushort)(r >> 16);
}

__device__ inline float bf2f(ushort u) {
    union { float f; unsigned v; } x; x.v = ((unsigned)u) << 16;
    return x.f;
}

// ============ Phase A: MFMA contrib producer (no atomics) ============
// One wave per 16-pair tile (grid-stride). A: 16 gathered feats rows
// (fp32 -> bf16 in-register). B even/odd interleave: MFMA half h computes
// channels 2*col+h, so each lane packs channels {2c,2c+1} into one dword
// store -> contrib row layout is standard [pair][32 ch] bf16.
__global__ __launch_bounds__(256) void contrib_mfma_kernel(
    const float* __restrict__ feats,
    const float* __restrict__ weight,
    const int* __restrict__ in_idx,
    unsigned* __restrict__ contrib,      // [K*P][16] dwords
    int P, int ntiles, int waves_per_k)
{
    const int k    = blockIdx.y;
    const int lane = threadIdx.x & 63;
    const int wav  = blockIdx.x * (blockDim.x >> 6) + (threadIdx.x >> 6);
    const int col  = lane & 15;
    const int kch  = lane >> 4;          // 0..3

    // B fragments from fp32 weight: bfrag[ks][h] covers k = ks*32+kch*8+e,
    // output channel 2*col+h.
    bf16x8 bfrag[2][2];
    const float* __restrict__ Wk = weight + (long)k * CIN * COUT;
    #pragma unroll
    for (int ks = 0; ks < 2; ++ks)
        #pragma unroll
        for (int h = 0; h < 2; ++h) {
            bf16x8 t;
            #pragma unroll
            for (int e = 0; e < 8; ++e)
                t[e] = (short)f2bf(Wk[(ks * 32 + kch * 8 + e) * COUT + 2 * col + h]);
            bfrag[ks][h] = t;
        }

    const int base = k * P;
    for (int tile = wav; tile < ntiles; tile += waves_per_k) {
        const int p0 = tile << 4;
        const int pA = min(p0 + col, P - 1);
        const int row = in_idx[base + pA];

        // Gather lane's 16 fp32 k-elements: [kch*8, +8) and [32+kch*8, +8).
        const float* __restrict__ ar = feats + (long)row * CIN + kch * 8;
        float4 f0 = *reinterpret_cast<const float4*>(ar);
        float4 f1 = *reinterpret_cast<const float4*>(ar + 4);
        float4 f2 = *reinterpret_cast<const float4*>(ar + 32);
        float4 f3 = *reinterpret_cast<const float4*>(ar + 36);

        bf16x8 a0, a1;
        a0[0] = (short)f2bf(f0.x); a0[1] = (short)f2bf(f0.y);
        a0[2] = (short)f2bf(f0.z); a0[3] = (short)f2bf(f0.w);
        a0[4] = (short)f2bf(f1.x); a0[5] = (short)f2bf(f1.y);
        a0[6] = (short)f2bf(f1.z); a0[7] = (short)f2bf(f1.w);
        a1[0] = (short)f2bf(f2.x); a1[1] = (short)f2bf(f2.y);
        a1[2] = (short)f2bf(f2.z); a1[3] = (short)f2bf(f2.w);
        a1[4] = (short)f2bf(f3.x); a1[5] = (short)f2bf(f3.y);
        a1[6] = (short)f2bf(f3.z); a1[7] = (short)f2bf(f3.w);

        f32x4 acc0 = {0.f, 0.f, 0.f, 0.f};
        f32x4 acc1 = {0.f, 0.f, 0.f, 0.f};
        acc0 = __builtin_amdgcn_mfma_f32_16x16x32_bf16(a0, bfrag[0][0], acc0, 0, 0, 0);
        acc0 = __builtin_amdgcn_mfma_f32_16x16x32_bf16(a1, bfrag[1][0], acc0, 0, 0, 0);
        acc1 = __builtin_amdgcn_mfma_f32_16x16x32_bf16(a0, bfrag[0][1], acc1, 0, 0, 0);
        acc1 = __builtin_amdgcn_mfma_f32_16x16x32_bf16(a1, bfrag[1][1], acc1, 0, 0, 0);

        #pragma unroll
        for (int r = 0; r < 4; ++r) {
            const int prow = p0 + kch * 4 + r;
            if (prow < P) {
                unsigned pk = (unsigned)f2bf(acc0[r]) |
                              ((unsigned)f2bf(acc1[r]) << 16);
                contrib[(long)(base + prow) * 16 + col] = pk;
            }
        }
    }
}

// ============ Phase B: CSR inversion of out_idx ============

__global__ __launch_bounds__(256) void zero_kernel(int4* __restrict__ rb, int n4)
{
    int i = blockIdx.x * blockDim.x + threadIdx.x;
    if (i < n4) rb[i] = int4{0, 0, 0, 0};
}

__global__ __launch_bounds__(256) void hist_kernel(
    const int* __restrict__ out_idx, int* __restrict__ rb, int total)
{
    int i = (blockIdx.x * blockDim.x + threadIdx.x) * 4;
    if (i + 3 < total) {
        int4 o = *reinterpret_cast<const int4*>(out_idx + i);
        atomicAdd(&rb[o.x], 1);
        atomicAdd(&rb[o.y], 1);
        atomicAdd(&rb[o.z], 1);
        atomicAdd(&rb[o.w], 1);
    } else {
        for (int j = i; j < total; ++j) atomicAdd(&rb[out_idx[j]], 1);
    }
}

__global__ __launch_bounds__(256) void scan_blocks_kernel(
    int* __restrict__ rb, int* __restrict__ bsums, int n)
{
    __shared__ int s[256];
    int i = blockIdx.x * 256 + threadIdx.x;
    int v = (i < n) ? rb[i] : 0;
    s[threadIdx.x] = v;
    __syncthreads();
    #pragma unroll
    for (int d = 1; d < 256; d <<= 1) {
        int t = (threadIdx.x >= d) ? s[threadIdx.x - d] : 0;
        __syncthreads();
        s[threadIdx.x] += t;
        __syncthreads();
    }
    if (i < n) rb[i] = s[threadIdx.x] - v;          // exclusive within block
    if (threadIdx.x == 255) bsums[blockIdx.x] = s[255];
}

#define MAXM 8
__global__ __launch_bounds__(256) void scan_bsums_kernel(int* __restrict__ bsums, int nb)
{
    __shared__ int s[256];
    const int t = threadIdx.x;
    const int base = t * MAXM;
    int loc[MAXM];
    int sum = 0;
    #pragma unroll
    for (int m = 0; m < MAXM; ++m) {
        int idx = base + m;
        int v = (idx < nb) ? bsums[idx] : 0;
        loc[m] = sum;
        sum += v;
    }
    s[t] = sum;
    __syncthreads();
    #pragma unroll
    for (int d = 1; d < 256; d <<= 1) {
        int tv = (t >= d) ? s[t - d] : 0;
        __syncthreads();
        s[t] += tv;
        __syncthreads();
    }
    int off = s[t] - sum;
    #pragma unroll
    for (int m = 0; m < MAXM; ++m) {
        int idx = base + m;
        if (idx < nb) bsums[idx] = off + loc[m];
    }
}

__global__ __launch_bounds__(256) void add_offsets_kernel(
    int* __restrict__ rb, const int* __restrict__ bsums, int n)
{
    int i = blockIdx.x * blockDim.x + threadIdx.x;
    if (i < n) rb[i] += bsums[i >> 8];
}

// After fill, rb[o] = end(o).
__global__ __launch_bounds__(256) void fill_kernel(
    const int* __restrict__ out_idx, int* __restrict__ rb,
    int* __restrict__ records, int total)
{
    int i = (blockIdx.x * blockDim.x + threadIdx.x) * 4;
    if (i + 3 < total) {
        int4 o = *reinterpret_cast<const int4*>(out_idx + i);
        records[atomicAdd(&rb[o.x], 1)] = i;
        records[atomicAdd(&rb[o.y], 1)] = i + 1;
        records[atomicAdd(&rb[o.z], 1)] = i + 2;
        records[atomicAdd(&rb[o.w], 1)] = i + 3;
    } else {
        for (int j = i; j < total; ++j)
            records[atomicAdd(&rb[out_idx[j]], 1)] = j;
    }
}

// ============ Phase C: per-row gather-reduce (breadth-first) ============
__global__ __launch_bounds__(256) void reduce_kernel(
    const ushort* __restrict__ contrib,
    const int* __restrict__ records,
    const int* __restrict__ rb,          // rb[o] = end(o)
    const float* __restrict__ bias,
    float* __restrict__ out, int n_out)
{
    int gid  = blockIdx.x * (blockDim.x >> 5) + (threadIdx.x >> 5);
    int lane = threadIdx.x & 31;
    if (gid >= n_out) return;

    int end   = rb[gid];
    int start = (gid == 0) ? 0 : rb[gid - 1];
    int m     = end - start;
    float acc = bias[lane];

    for (int b = 0; b < m; b += 32) {
        int nn = min(32, m - b);
        int rec = (lane < nn) ? records[start + b + lane] : 0;
        for (int j = 0; j < nn; ++j) {
            int r = __shfl(rec, j, 32);
            acc += bf2f(contrib[(long)r * COUT + lane]);  // independent 64B loads
        }
    }
    out[(long)gid * COUT + lane] = acc;
}

// ============ Fallback (R2 atomic path, no workspace) ============

__global__ __launch_bounds__(256) void bias_init_kernel(
    float* __restrict__ out, const float* __restrict__ bias, int total)
{
    int i = (blockIdx.x * blockDim.x + threadIdx.x) * 4;
    if (i < total) {
        int ch = i & (COUT - 1);
        float4 b;
        b.x = bias[ch + 0]; b.y = bias[ch + 1];
        b.z = bias[ch + 2]; b.w = bias[ch + 3];
        *reinterpret_cast<float4*>(out + i) = b;
    }
}

__global__ __launch_bounds__(256) void scatter_gemm_kernel(
    const float* __restrict__ feats,
    const float* __restrict__ weight,
    const int* __restrict__ in_idx,
    const int* __restrict__ out_idx,
    float* __restrict__ out,
    int P, int n_groups)
{
    const int k        = blockIdx.y;
    const int lane     = threadIdx.x & 31;
    const int group_id = blockIdx.x * (blockDim.x >> 5) + (threadIdx.x >> 5);

    float w[CIN];
    const float* __restrict__ Wk = weight + (long)k * CIN * COUT;
    #pragma unroll
    for (int c = 0; c < CIN; ++c) w[c] = Wk[c * COUT + lane];

    const int base    = k * P;
    const int nchunks = (P + 31) >> 5;
    for (int ch = group_id; ch < nchunks; ch += n_groups) {
        const int p0 = ch << 5;
        const int n  = min(32, P - p0);
        int my_in = 0, my_out = 0;
        if (lane < n) {
            my_in  = in_idx[base + p0 + lane];
            my_out = out_idx[base + p0 + lane];
        }
        #pragma unroll 4
        for (int j = 0; j < n; ++j) {
            const int in = __shfl(my_in,  j, 32);
            const int o  = __shfl(my_out, j, 32);
            const float4* __restrict__ fr =
                reinterpret_cast<const float4*>(feats + (long)in * CIN);
            float acc = 0.0f;
            #pragma unroll
            for (int c4 = 0; c4 < CIN / 4; ++c4) {
                float4 f = fr[c4];
                acc += f.x * w[4 * c4 + 0];
                acc += f.y * w[4 * c4 + 1];
                acc += f.z * w[4 * c4 + 2];
                acc += f.w * w[4 * c4 + 3];
            }
            atomicAdd(out + (long)o * COUT + lane, acc);
        }
    }
}

// ============ launch ============

extern "C" void kernel_launch(void* const* d_in, const int* in_sizes, int n_in,
                              void* d_out, int out_size, void* d_ws, size_t ws_size,
                              hipStream_t stream) {
    const float* feats   = (const float*)d_in[0];
    const float* weight  = (const float*)d_in[1];
    const float* bias    = (const float*)d_in[2];
    const int*   in_idx  = (const int*)d_in[3];
    const int*   out_idx = (const int*)d_in[4];
    float*       out     = (float*)d_out;

    const int K     = in_sizes[1] / (CIN * COUT);   // 27
    const int P     = in_sizes[3] / K;              // 50000
    const int total = K * P;                        // 1.35M
    const int n_out = out_size / COUT;              // 400000
    const int nblk  = (n_out + 255) / 256;          // 1563

    size_t off = 0;
    auto take = [&](size_t bytes) {
        size_t o = off;
        off = (off + bytes + 255) & ~(size_t)255;
        return o;
    };
    size_t rb_off      = take((size_t)n_out * 4);
    size_t bsums_off   = take((size_t)nblk * 4);
    size_t records_off = take((size_t)total * 4);
    size_t contrib_off = take((size_t)total * COUT * 2);

    if (off > ws_size || nblk > 256 * MAXM || (n_out & 3) != 0) {
        int total4 = out_size / 4;
        bias_init_kernel<<<(total4 + 255) / 256, 256, 0, stream>>>(out, bias, out_size);
        const int blocks_x = 96;
        const int n_groups = blocks_x * (256 / 32);
        dim3 grid(blocks_x, K);
        scatter_gemm_kernel<<<grid, 256, 0, stream>>>(feats, weight, in_idx, out_idx,
                                                      out, P, n_groups);
        return;
    }

    char* ws = (char*)d_ws;
    int*      rb      = (int*)(ws + rb_off);
    int*      bsums   = (int*)(ws + bsums_off);
    int*      records = (int*)(ws + records_off);
    unsigned* contrib = (unsigned*)(ws + contrib_off);

    // Phase A: MFMA contributions (plain stores).
    {
        const int ntiles   = (P + 15) / 16;
        const int blocks_x = 196;
        const int waves_per_k = blocks_x * (256 / 64);
        dim3 grid(blocks_x, K);
        contrib_mfma_kernel<<<grid, 256, 0, stream>>>(feats, weight, in_idx,
                                                      contrib, P, ntiles, waves_per_k);
    }

    // Phase B: CSR inversion.
    zero_kernel<<<(n_out / 4 + 255) / 256, 256, 0, stream>>>((int4*)rb, n_out / 4);
    hist_kernel<<<(total / 4 + 255) / 256, 256, 0, stream>>>(out_idx, rb, total);
    scan_blocks_kernel<<<nblk, 256, 0, stream>>>(rb, bsums, n_out);
    scan_bsums_kernel<<<1, 256, 0, stream>>>(bsums, nblk);
    add_offsets_kernel<<<(n_out + 255) / 256, 256, 0, stream>>>(rb, bsums, n_out);
    fill_kernel<<<(total / 4 + 255) / 256, 256, 0, stream>>>(out_idx, rb, records, total);

    // Phase C: gather-reduce + bias, single coalesced store per row.
    reduce_kernel<<<(n_out * 32 + 255) / 256, 256, 0, stream>>>(
        (const ushort*)contrib, records, rb, bias, out, n_out);
}

// Round 6
// 108.651 us; speedup vs baseline: 2.8014x; 2.8014x over previous
//
#include <hip/hip_runtime.h>

#define CIN 64
#define COUT 32

typedef __attribute__((ext_vector_type(8))) short bf16x8;
typedef __attribute__((ext_vector_type(4))) float f32x4;

__device__ inline ushort f2bf(float x) {
    union { float f; unsigned u; } v; v.f = x;
    unsigned r = v.u + 0x7fff + ((v.u >> 16) & 1);   // RNE
    return (ushort)(r >> 16);
}

// fp32 -> bf16 conversion, 4 elems/thread (for feats).
__global__ __launch_bounds__(256) void cvt_kernel(
    const float* __restrict__ in, ushort* __restrict__ outb, int n4)
{
    int i = blockIdx.x * blockDim.x + threadIdx.x;
    if (i < n4) {
        float4 f = reinterpret_cast<const float4*>(in)[i];
        ushort4 u;
        u.x = f2bf(f.x); u.y = f2bf(f.y); u.z = f2bf(f.z); u.w = f2bf(f.w);
        reinterpret_cast<ushort4*>(outb)[i] = u;
    }
}

// Zero the fp16 accumulator buffer (uint4 = 8 halves per thread).
__global__ __launch_bounds__(256) void zero16_kernel(uint4* __restrict__ p, int n16)
{
    int i = blockIdx.x * blockDim.x + threadIdx.x;
    if (i < n16) p[i] = uint4{0u, 0u, 0u, 0u};
}

// MFMA gather-GEMM -> packed v2f16 atomic scatter.
// B even/odd interleave: acc0[r] = channel 2*col, acc1[r] = channel 2*col+1
// (verified in R5) -> one global_atomic_pk_add_f16 per lane per output row.
__global__ __launch_bounds__(256) void mfma_scatter_pk_kernel(
    const ushort* __restrict__ featsb,   // [N_IN][64] bf16
    const float* __restrict__ weight,    // [K][64][32] fp32
    const int* __restrict__ in_idx,
    const int* __restrict__ out_idx,
    ushort* __restrict__ outh,           // [n_out][32] fp16 accumulator
    int P, int ntiles, int waves_per_k)
{
    const int k    = blockIdx.y;
    const int lane = threadIdx.x & 63;
    const int wav  = blockIdx.x * (blockDim.x >> 6) + (threadIdx.x >> 6);
    const int col  = lane & 15;
    const int kch  = lane >> 4;          // 0..3

    // B fragments: bfrag[ks][h] covers k = ks*32+kch*8+e, out channel 2*col+h.
    bf16x8 bfrag[2][2];
    const float* __restrict__ Wk = weight + (long)k * CIN * COUT;
    #pragma unroll
    for (int ks = 0; ks < 2; ++ks)
        #pragma unroll
        for (int h = 0; h < 2; ++h) {
            bf16x8 t;
            #pragma unroll
            for (int e = 0; e < 8; ++e)
                t[e] = (short)f2bf(Wk[(ks * 32 + kch * 8 + e) * COUT + 2 * col + h]);
            bfrag[ks][h] = t;
        }

    const int base = k * P;
    for (int tile = wav; tile < ntiles; tile += waves_per_k) {
        const int p0 = tile << 4;
        const int pA = min(p0 + col, P - 1);
        const int row = in_idx[base + pA];

        const ushort* __restrict__ ar = featsb + (long)row * CIN + kch * 8;
        bf16x8 a0 = *reinterpret_cast<const bf16x8*>(ar);
        bf16x8 a1 = *reinterpret_cast<const bf16x8*>(ar + 32);

        f32x4 acc0 = {0.f, 0.f, 0.f, 0.f};
        f32x4 acc1 = {0.f, 0.f, 0.f, 0.f};
        acc0 = __builtin_amdgcn_mfma_f32_16x16x32_bf16(a0, bfrag[0][0], acc0, 0, 0, 0);
        acc0 = __builtin_amdgcn_mfma_f32_16x16x32_bf16(a1, bfrag[1][0], acc0, 0, 0, 0);
        acc1 = __builtin_amdgcn_mfma_f32_16x16x32_bf16(a0, bfrag[0][1], acc1, 0, 0, 0);
        acc1 = __builtin_amdgcn_mfma_f32_16x16x32_bf16(a1, bfrag[1][1], acc1, 0, 0, 0);

        #pragma unroll
        for (int r = 0; r < 4; ++r) {
            const int prow = p0 + kch * 4 + r;
            if (prow < P) {
                const int orow = out_idx[base + prow];
                // Pack channels {2*col, 2*col+1} as v2f16 (RNE via scalar cvt).
                union { _Float16 h[2]; unsigned u; } pk;
                pk.h[0] = (_Float16)acc0[r];
                pk.h[1] = (_Float16)acc1[r];
                const ushort* dst = outh + (long)orow * COUT + 2 * col;
                asm volatile("global_atomic_pk_add_f16 %0, %1, off"
                             :: "v"((unsigned long long)dst), "v"(pk.u)
                             : "memory");
            }
        }
    }
}

// out[i] = fp32(outh[i]) + bias[ch], 4 channels per thread.
__global__ __launch_bounds__(256) void finalize_kernel(
    const unsigned* __restrict__ outh_u, const float* __restrict__ bias,
    float* __restrict__ out, int n4)
{
    int i = blockIdx.x * blockDim.x + threadIdx.x;
    if (i < n4) {
        unsigned u0 = outh_u[2 * i], u1 = outh_u[2 * i + 1];
        int ch = (i * 4) & (COUT - 1);
        union { unsigned u; _Float16 h[2]; } a, b;
        a.u = u0; b.u = u1;
        float4 o;
        o.x = (float)a.h[0] + bias[ch + 0];
        o.y = (float)a.h[1] + bias[ch + 1];
        o.z = (float)b.h[0] + bias[ch + 2];
        o.w = (float)b.h[1] + bias[ch + 3];
        reinterpret_cast<float4*>(out)[i] = o;
    }
}

// ============ Fallback (R2 atomic path, no workspace) ============

__global__ __launch_bounds__(256) void bias_init_kernel(
    float* __restrict__ out, const float* __restrict__ bias, int total)
{
    int i = (blockIdx.x * blockDim.x + threadIdx.x) * 4;
    if (i < total) {
        int ch = i & (COUT - 1);
        float4 b;
        b.x = bias[ch + 0]; b.y = bias[ch + 1];
        b.z = bias[ch + 2]; b.w = bias[ch + 3];
        *reinterpret_cast<float4*>(out + i) = b;
    }
}

__global__ __launch_bounds__(256) void scatter_gemm_kernel(
    const float* __restrict__ feats,
    const float* __restrict__ weight,
    const int* __restrict__ in_idx,
    const int* __restrict__ out_idx,
    float* __restrict__ out,
    int P, int n_groups)
{
    const int k        = blockIdx.y;
    const int lane     = threadIdx.x & 31;
    const int group_id = blockIdx.x * (blockDim.x >> 5) + (threadIdx.x >> 5);

    float w[CIN];
    const float* __restrict__ Wk = weight + (long)k * CIN * COUT;
    #pragma unroll
    for (int c = 0; c < CIN; ++c) w[c] = Wk[c * COUT + lane];

    const int base    = k * P;
    const int nchunks = (P + 31) >> 5;
    for (int ch = group_id; ch < nchunks; ch += n_groups) {
        const int p0 = ch << 5;
        const int n  = min(32, P - p0);
        int my_in = 0, my_out = 0;
        if (lane < n) {
            my_in  = in_idx[base + p0 + lane];
            my_out = out_idx[base + p0 + lane];
        }
        #pragma unroll 4
        for (int j = 0; j < n; ++j) {
            const int in = __shfl(my_in,  j, 32);
            const int o  = __shfl(my_out, j, 32);
            const float4* __restrict__ fr =
                reinterpret_cast<const float4*>(feats + (long)in * CIN);
            float acc = 0.0f;
            #pragma unroll
            for (int c4 = 0; c4 < CIN / 4; ++c4) {
                float4 f = fr[c4];
                acc += f.x * w[4 * c4 + 0];
                acc += f.y * w[4 * c4 + 1];
                acc += f.z * w[4 * c4 + 2];
                acc += f.w * w[4 * c4 + 3];
            }
            atomicAdd(out + (long)o * COUT + lane, acc);
        }
    }
}

// ============ launch ============

extern "C" void kernel_launch(void* const* d_in, const int* in_sizes, int n_in,
                              void* d_out, int out_size, void* d_ws, size_t ws_size,
                              hipStream_t stream) {
    const float* feats   = (const float*)d_in[0];
    const float* weight  = (const float*)d_in[1];
    const float* bias    = (const float*)d_in[2];
    const int*   in_idx  = (const int*)d_in[3];
    const int*   out_idx = (const int*)d_in[4];
    float*       out     = (float*)d_out;

    const int K      = in_sizes[1] / (CIN * COUT);  // 27
    const int P      = in_sizes[3] / K;             // 50000
    const int n_feat = in_sizes[0];                 // N_IN*CIN (12.8M)
    const int n_out  = out_size / COUT;             // 400000

    // ws: bf16 feats + fp16 accumulator.
    size_t featsb_bytes = (size_t)n_feat * 2;
    size_t outh_off     = (featsb_bytes + 255) & ~(size_t)255;
    size_t need         = outh_off + (size_t)out_size * 2;

    if (need > ws_size || (out_size & 3) != 0) {
        int total4 = out_size / 4;
        bias_init_kernel<<<(total4 + 255) / 256, 256, 0, stream>>>(out, bias, out_size);
        const int blocks_x = 96;
        const int n_groups = blocks_x * (256 / 32);
        dim3 grid(blocks_x, K);
        scatter_gemm_kernel<<<grid, 256, 0, stream>>>(feats, weight, in_idx, out_idx,
                                                      out, P, n_groups);
        return;
    }

    ushort* featsb = (ushort*)d_ws;
    ushort* outh   = (ushort*)((char*)d_ws + outh_off);

    // Prep: bf16 feats; zero fp16 accumulator.
    cvt_kernel<<<(n_feat / 4 + 255) / 256, 256, 0, stream>>>(feats, featsb, n_feat / 4);
    {
        int n16 = (out_size * 2) / 16;   // out_size halves * 2B / 16B
        zero16_kernel<<<(n16 + 255) / 256, 256, 0, stream>>>((uint4*)outh, n16);
    }

    // Main: MFMA gather-GEMM + packed-f16 atomic scatter.
    {
        const int ntiles      = (P + 15) / 16;
        const int blocks_x    = 196;
        const int waves_per_k = blocks_x * (256 / 64);
        dim3 grid(blocks_x, K);
        mfma_scatter_pk_kernel<<<grid, 256, 0, stream>>>(featsb, weight, in_idx,
                                                         out_idx, outh, P, ntiles,
                                                         waves_per_k);
    }

    // Finalize: widen + bias.
    finalize_kernel<<<(out_size / 4 + 255) / 256, 256, 0, stream>>>(
        (const unsigned*)outh, bias, out, out_size / 4);
}